// Round 1
// baseline (17507.809 us; speedup 1.0000x reference)
//
#include <hip/hip_runtime.h>
#include <hip/hip_bf16.h>
#include <stdint.h>

typedef __attribute__((ext_vector_type(8))) short s16x8;   // 8 bf16 (4 VGPRs)
typedef __attribute__((ext_vector_type(4))) float f32x4;
typedef unsigned short u16;
typedef unsigned int u32;

#define FEAT 2048
#define HID  512
#define GATES 2048   // 4*HID
#define NB   16
#define NT   2048
#define NOUT 22
#define MROWS (NB*NT)   // 32768

// ---- workspace layout (bytes) ----
#define WS_FLAG 0L
#define WS_CNT  256L                       // cnt[lstm] at +lstm*256
#define WS_HBUF 4096L                      // [2 buf][2 lstm][16 b][512 hid] u16 = 131072
#define WS_BIAS (WS_HBUF + 131072L)        // [2][2048] f32 = 16384
#define WS_WHB  (WS_BIAS + 16384L)         // [2][2048][512] u16 = 4 MiB
#define WS_WB   (WS_WHB + 4194304L)        // [2][2048][2048] u16 = 16 MiB
#define WS_XB   (WS_WB + 16777216L)        // x as bf16: 64M u16 = 128 MiB
#define WS_XG   (WS_XB + 134217728L)       // [2][32768][2048] u16 = 256 MiB
#define WS_HS   (WS_XG + 268435456L)       // [2][16][2048][512] u16 = 64 MiB

__device__ inline float b2f(u16 u){ u32 x = ((u32)u) << 16; return __builtin_bit_cast(float, x); }
__device__ inline u16 f2b(float f){
  u32 u = __builtin_bit_cast(u32, f);
  u32 r = (u + 0x7FFFu + ((u >> 16) & 1u)) >> 16;   // RNE
  return (u16)r;
}
__device__ inline float sigm(float x){ return __builtin_amdgcn_rcpf(1.f + __expf(-x)); }
__device__ inline float tanh_(float x){ return 1.f - 2.f*__builtin_amdgcn_rcpf(1.f + __expf(2.f*x)); }

// ---------------- dtype detector ----------------
// bf16-packed buffers: low ushort of each u32 word is itself a bf16 of ~N(0,1)
// -> exponent field concentrated in [110,134]. fp32 buffers: low 16 bits are
// uniform mantissa bits -> ~10% hit rate. Threshold at 50% over 4096 words.
__global__ void detect_dtype(const u32* __restrict__ x, int* __restrict__ flag){
  __shared__ int cs;
  if (threadIdx.x == 0) cs = 0;
  __syncthreads();
  int c = 0;
  for (int i = 0; i < 16; i++){
    u32 w = x[threadIdx.x*16 + i];
    u32 e = (w >> 7) & 0xFFu;
    if ((e >= 110u && e <= 134u) || ((w & 0xFFFFu) == 0u)) c++;
  }
  atomicAdd(&cs, c);
  __syncthreads();
  if (threadIdx.x == 0) *flag = (cs > 2048) ? 1 : 0;
}

// ---------------- fp32|bf16 -> bf16 conversion/copy (8 elems per thread) ----
__global__ void cvt_bf16(const void* __restrict__ src, u16* __restrict__ dst,
                         long n8, const int* __restrict__ flag){
  const int isb = *flag;
  long stride = (long)gridDim.x * blockDim.x;
  for (long i = (long)blockIdx.x*blockDim.x + threadIdx.x; i < n8; i += stride){
    if (isb){
      ((int4*)dst)[i] = ((const int4*)src)[i];
    } else {
      const float4* s = (const float4*)src + 2*i;
      float4 a = s[0], b = s[1];
      s16x8 o;
      o[0]=(short)f2b(a.x); o[1]=(short)f2b(a.y); o[2]=(short)f2b(a.z); o[3]=(short)f2b(a.w);
      o[4]=(short)f2b(b.x); o[5]=(short)f2b(b.y); o[6]=(short)f2b(b.z); o[7]=(short)f2b(b.w);
      *(s16x8*)(dst + i*8) = o;
    }
  }
}

// ---------------- bias combine: b_ih + b_hh (both LSTMs) ----------------
__global__ void bias_sum(const void* bi0, const void* bh0, const void* bi1, const void* bh1,
                         float* __restrict__ out, const int* __restrict__ flag){
  const int isb = *flag;
  int i = blockIdx.x*256 + threadIdx.x;     // 0..4095
  int lstm = i >> 11, idx = i & 2047;
  const void* bi = lstm ? bi1 : bi0;
  const void* bh = lstm ? bh1 : bh0;
  float a = isb ? b2f(((const u16*)bi)[idx]) : ((const float*)bi)[idx];
  float b = isb ? b2f(((const u16*)bh)[idx]) : ((const float*)bh)[idx];
  out[i] = a + b;
}

// ---------------- xg GEMM: xg[lstm][b*T+t][j] = x @ W_ih^T + bias ----------
// 128x128 tile, BK=64, 4 waves (2x2), 2-phase double buffer, global_load_lds
// with st-swizzle (linear LDS dest + inverse-swizzled global source, T2/rule21).
__global__ __launch_bounds__(256,2) void gemm_xg(const u16* __restrict__ xb,
    const u16* __restrict__ wb, const float* __restrict__ bias, u16* __restrict__ xg){
  __shared__ u16 As[2][128*64];
  __shared__ u16 Bs[2][128*64];
  const int lstm = blockIdx.z;
  const int n0 = blockIdx.x * 128;
  const int m0 = blockIdx.y * 128;
  const int tid = threadIdx.x;
  const int lane = tid & 63;
  const int wid = tid >> 6;
  const int wr = wid >> 1, wc = wid & 1;
  const u16* Bw = wb + (size_t)lstm * GATES * FEAT;   // [N=2048][K=2048] (already B^T)

  f32x4 acc[4][4] = {};

  auto stage = [&](int buf, int kt){
    const int k0 = kt*64;
#pragma unroll
    for (int i = 0; i < 4; i++){
      int cc = tid + 256*i;             // 16B chunk id, 0..1023
      int row = cc >> 3;                // 0..127
      int slot = cc & 7;                // 8 x 16B per 128B row
      int slotp = slot ^ (row & 7);     // inverse-swizzled source
      const u16* ga = xb + (size_t)(m0+row)*FEAT + k0 + slotp*8;
      const u16* gb = Bw + (size_t)(n0+row)*FEAT + k0 + slotp*8;
      __builtin_amdgcn_global_load_lds((const __attribute__((address_space(1))) void*)ga,
          (__attribute__((address_space(3))) void*)&As[buf][cc*8], 16, 0, 0);
      __builtin_amdgcn_global_load_lds((const __attribute__((address_space(1))) void*)gb,
          (__attribute__((address_space(3))) void*)&Bs[buf][cc*8], 16, 0, 0);
    }
  };

  stage(0, 0);
  __syncthreads();
  for (int kt = 0; kt < 32; kt++){
    int buf = kt & 1;
    if (kt < 31) stage(buf^1, kt+1);
    const char* Ab = (const char*)&As[buf][0];
    const char* Bb = (const char*)&Bs[buf][0];
#pragma unroll
    for (int ks = 0; ks < 2; ks++){
      s16x8 af[4], bf[4];
#pragma unroll
      for (int mi = 0; mi < 4; mi++){
        int row = wr*64 + mi*16 + (lane & 15);
        int off = row*128 + ((ks*64 + ((lane>>4)*16)) ^ ((row & 7) << 4));
        af[mi] = *(const s16x8*)(Ab + off);
      }
#pragma unroll
      for (int ni = 0; ni < 4; ni++){
        int row = wc*64 + ni*16 + (lane & 15);
        int off = row*128 + ((ks*64 + ((lane>>4)*16)) ^ ((row & 7) << 4));
        bf[ni] = *(const s16x8*)(Bb + off);
      }
#pragma unroll
      for (int mi = 0; mi < 4; mi++)
#pragma unroll
        for (int ni = 0; ni < 4; ni++)
          acc[mi][ni] = __builtin_amdgcn_mfma_f32_16x16x32_bf16(af[mi], bf[ni], acc[mi][ni], 0, 0, 0);
    }
    __syncthreads();   // drains vmcnt: next-tile stage complete for everyone
  }

  u16* xgl = xg + (size_t)lstm * MROWS * GATES;
#pragma unroll
  for (int mi = 0; mi < 4; mi++){
#pragma unroll
    for (int ni = 0; ni < 4; ni++){
      int gcol = n0 + wc*64 + ni*16 + (lane & 15);
      float bv = bias[lstm*GATES + gcol];
#pragma unroll
      for (int r = 0; r < 4; r++){
        int grow = m0 + wr*64 + mi*16 + ((lane>>4)<<2) + r;   // C/D: row=(l>>4)*4+r
        xgl[(size_t)grow*GATES + gcol] = f2b(acc[mi][ni][r] + bv);
      }
    }
  }
}

// ---------------- persistent recurrent kernel ----------------
// 32 WGs: [lstm (2)] x [w (16 hidden-slices of 32)]. 512 threads = 8 waves.
// Wave wv owns 16 MFMA columns n=0..15 -> gate row j = (n&3)*512 + w*32 + wv*4 + (n>>2).
// W_hh fragments live permanently in VGPRs (64/lane). h exchanged via global
// hbuf (double buffered) + per-LSTM monotonic arrival counter (device scope).
__global__ __launch_bounds__(512,1) void lstm_rec(const u16* __restrict__ whb,
    const u16* __restrict__ xg, u16* __restrict__ hbuf, u16* __restrict__ hs,
    u32* __restrict__ cnt){
  const int blk = blockIdx.x;
  const int lstm = blk >> 4;
  const int w = blk & 15;
  const int tid = threadIdx.x;
  const int lane = tid & 63;
  const int wv = tid >> 6;
  const int n = lane & 15;
  const int q = n & 3;                         // gate: 0=i,1=f,2=g,3=o
  const int hid = w*32 + wv*4 + (n >> 2);
  const int j = q*512 + hid;                   // gate row in [0,2048)
  const int kh = (lane >> 4) * 8;              // k-chunk base within 32
  const int b0 = (lane >> 4) * 4;              // batches b0..b0+3 (C/D rows)

  // resident W_hh fragments: wf[kk] = W[j][kk*32 + kh .. +8]
  s16x8 wf[16];
  {
    const u16* wrow = whb + ((size_t)lstm*GATES + j) * HID;
#pragma unroll
    for (int kk = 0; kk < 16; kk++)
      wf[kk] = *(const s16x8*)(wrow + kk*32 + kh);
  }

  u32* myc = cnt + (size_t)lstm * 64;          // 256B apart
  const size_t HBL = (size_t)2*16*512;         // elems per buffer (both lstms)
  u16* hsl = hs + (size_t)lstm * NB * NT * HID;

  const u16* xp[4];
  u16 xv[4], xn[4];
#pragma unroll
  for (int r = 0; r < 4; r++){
    xp[r] = xg + (size_t)lstm*MROWS*GATES + (size_t)(b0+r)*NT*GATES + j;
    xv[r] = xp[r][0];
  }
  float c[4] = {0.f, 0.f, 0.f, 0.f};

  for (int t = 0; t < NT; t++){
    if (t > 0){
      if (tid == 0){
        u32 tgt = 16u * (u32)t;
        while (__hip_atomic_load(myc, __ATOMIC_RELAXED, __HIP_MEMORY_SCOPE_AGENT) < tgt)
          __builtin_amdgcn_s_sleep(2);
      }
      __syncthreads();
      __builtin_amdgcn_fence(__ATOMIC_ACQUIRE, "agent");
    }
    // A-fragments: h(t) for batch row (lane&15), k-chunk kh
    const u16* hcur = hbuf + (size_t)(t & 1)*HBL + (size_t)lstm*16*512
                      + (size_t)n*512 + kh;
    f32x4 acc = {0.f, 0.f, 0.f, 0.f};
#pragma unroll
    for (int kk = 0; kk < 16; kk++){
      s16x8 af = *(const s16x8*)(hcur + kk*32);
      acc = __builtin_amdgcn_mfma_f32_16x16x32_bf16(af, wf[kk], acc, 0, 0, 0);
    }
    const int base = lane & 60;   // 4-lane gate group
    u16 hob[4];
#pragma unroll
    for (int r = 0; r < 4; r++){
      float g  = acc[r] + b2f(xv[r]);
      float iv = __shfl(g, base + 0, 64);
      float fv = __shfl(g, base + 1, 64);
      float gv = __shfl(g, base + 2, 64);
      float ov = __shfl(g, base + 3, 64);
      float cn = sigm(fv)*c[r] + sigm(iv)*tanh_(gv);
      c[r] = cn;
      hob[r] = f2b(sigm(ov)*tanh_(cn));
    }
    // prefetch next step's xg while nobody depends on it
    int tn = (t < NT-1) ? (t+1) : t;
#pragma unroll
    for (int r = 0; r < 4; r++) xn[r] = xp[r][(size_t)tn * GATES];
    // publish h(t+1) slice (q==0 lanes canonical) + hs for the heads
    u16* hnxt = hbuf + (size_t)((t+1) & 1)*HBL + (size_t)lstm*16*512;
    if (q == 0){
#pragma unroll
      for (int r = 0; r < 4; r++){
        hnxt[(size_t)(b0+r)*512 + hid] = hob[r];
        hsl[(size_t)(b0+r)*NT*HID + (size_t)t*HID + hid] = hob[r];
      }
    }
#pragma unroll
    for (int r = 0; r < 4; r++) xv[r] = xn[r];
    __syncthreads();   // drains vmcnt: this WG's stores complete
    if (tid == 0)
      __hip_atomic_fetch_add(myc, 1u, __ATOMIC_RELEASE, __HIP_MEMORY_SCOPE_AGENT);
  }
}

// ---------------- linear heads: out = hs @ fc_w^T + fc_b ----------------
__global__ __launch_bounds__(256,4) void head_fc(const u16* __restrict__ hs,
    const void* fcw0, const void* fcb0, const void* fcw1, const void* fcb1,
    void* __restrict__ dout, const int* __restrict__ flag){
  const int isb = *flag;
  const int lane = threadIdx.x & 63;
  const int wv = threadIdx.x >> 6;
  int row = blockIdx.x*4 + wv;                 // 0..65535 (= lstm*32768 + b*2048 + t)
  const int lstm = row >> 15;
  const int rem = row & 32767;
  const u16* hrow = hs + (size_t)row * HID;
  float hv[8];
  {
    s16x8 h8 = *(const s16x8*)(hrow + lane*8);
#pragma unroll
    for (int e = 0; e < 8; e++) hv[e] = b2f((u16)h8[e]);
  }
  const void* fcw = lstm ? fcw1 : fcw0;
  const void* fcb = lstm ? fcb1 : fcb0;
  float bval = 0.f;
  if (lane < NOUT) bval = isb ? b2f(((const u16*)fcb)[lane]) : ((const float*)fcb)[lane];
  float res = 0.f;
  for (int o = 0; o < NOUT; o++){
    float p = 0.f;
    if (isb){
      s16x8 w8 = *(const s16x8*)((const u16*)fcw + (size_t)o*HID + lane*8);
#pragma unroll
      for (int e = 0; e < 8; e++) p += hv[e] * b2f((u16)w8[e]);
    } else {
      const float* wr = (const float*)fcw + (size_t)o*HID + lane*8;
#pragma unroll
      for (int e = 0; e < 8; e++) p += hv[e] * wr[e];
    }
#pragma unroll
    for (int d = 1; d < 64; d <<= 1) p += __shfl_xor(p, d, 64);
    if (lane == o) res = p + bval;
  }
  size_t off = (size_t)lstm*(MROWS*NOUT) + (size_t)rem*NOUT;
  if (lane < NOUT){
    if (isb) ((u16*)dout)[off + lane] = f2b(res);
    else     ((float*)dout)[off + lane] = res;
  }
}

extern "C" void kernel_launch(void* const* d_in, const int* in_sizes, int n_in,
                              void* d_out, int out_size, void* d_ws, size_t ws_size,
                              hipStream_t stream){
  char* ws = (char*)d_ws;
  int*   flag = (int*)(ws + WS_FLAG);
  u32*   cnt  = (u32*)(ws + WS_CNT);
  u16*   hbuf = (u16*)(ws + WS_HBUF);
  float* bias = (float*)(ws + WS_BIAS);
  u16*   whb  = (u16*)(ws + WS_WHB);
  u16*   wb   = (u16*)(ws + WS_WB);
  u16*   xb   = (u16*)(ws + WS_XB);
  u16*   xg   = (u16*)(ws + WS_XG);
  u16*   hs   = (u16*)(ws + WS_HS);

  // zero flag + counters + h double-buffer (re-done every replay)
  hipMemsetAsync(ws, 0, (size_t)WS_BIAS, stream);

  detect_dtype<<<1, 256, 0, stream>>>((const u32*)d_in[0], flag);

  cvt_bf16<<<2048, 256, 0, stream>>>(d_in[0], xb,             67108864L/8, flag); // x
  cvt_bf16<<<2048, 256, 0, stream>>>(d_in[1], wb,              4194304L/8, flag); // w_ih
  cvt_bf16<<<2048, 256, 0, stream>>>(d_in[5], wb + 4194304L,   4194304L/8, flag); // w_ih_ed
  cvt_bf16<<< 512, 256, 0, stream>>>(d_in[2], whb,             1048576L/8, flag); // w_hh
  cvt_bf16<<< 512, 256, 0, stream>>>(d_in[6], whb + 1048576L,  1048576L/8, flag); // w_hh_ed
  bias_sum<<<16, 256, 0, stream>>>(d_in[3], d_in[4], d_in[7], d_in[8], bias, flag);

  gemm_xg<<<dim3(16, 256, 2), 256, 0, stream>>>(xb, wb, bias, xg);
  lstm_rec<<<32, 512, 0, stream>>>(whb, xg, hbuf, hs, cnt);
  head_fc<<<16384, 256, 0, stream>>>(hs, d_in[9], d_in[10], d_in[11], d_in[12], d_out, flag);
}